// Round 10
// baseline (520.367 us; speedup 1.0000x reference)
//
#include <hip/hip_runtime.h>
#include <hip/hip_bf16.h>

#define HEADS 8
#define DK 64
#define DV 64
#define DM 512
#define ROUNDS 2
#define SEQ 4096
#define BUCKET 64
#define NCHUNK 64
#define BATCH 4

typedef __hip_bfloat16 bf16;
__device__ __forceinline__ float b2f(bf16 x) { return __bfloat162float(x); }

// ---------------------------------------------------------------------------
// Kernel 1: hash. h[r][b][s] = argmax([q@R, -q@R]) + 1, in 1..64.
// RAW fp32 inputs, fp64 accumulation: exact argmax of the fp32 inputs
// (matches an fp64 np reference bit-exactly, immune to order differences).
// ---------------------------------------------------------------------------
__global__ __launch_bounds__(256) void hash_kernel(const float* __restrict__ q,
                                                   const float* __restrict__ R,
                                                   int* __restrict__ h_out) {
  int blk = blockIdx.x;
  int stile = blk & 63;
  int b = (blk >> 6) & (BATCH - 1);
  int r = blk >> 8;
  __shared__ float Rl[DM * 32];  // 64 KB
  for (int i = threadIdx.x; i < DM * 32; i += 256)
    Rl[i] = R[(size_t)r * DM * 32 + i];
  __syncthreads();
  int wave = threadIdx.x >> 6;
  int lane = threadIdx.x & 63;
  int m = lane & 31;
  int dbase = (lane >> 5) << 8;  // 0 or 256
  for (int pi = wave; pi < 64; pi += 4) {
    int s = (stile << 6) + pi;
    const float* qrow = q + ((size_t)b * SEQ + s) * DM;
    double acc = 0.0;
#pragma unroll 4
    for (int t = 0; t < 256; ++t) {
      int d = dbase + t;
      acc = fma((double)qrow[d], (double)Rl[d * 32 + m], acc);
    }
    acc += __shfl_xor(acc, 32);             // full rot_m on every lane
    double val = (lane < 32) ? acc : -acc;  // candidates [rot, -rot]
    int idx = lane;
    for (int off = 32; off >= 1; off >>= 1) {
      double ov = __shfl_down(val, off);
      int oi = __shfl_down(idx, off);
      if (ov > val || (ov == val && oi < idx)) { val = ov; idx = oi; }
    }
    if (lane == 0) h_out[((size_t)(r * BATCH + b)) * SEQ + s] = idx + 1;
  }
}

// ---------------------------------------------------------------------------
// Kernel 2: stable counting sort by bucket per (r,b).
// ---------------------------------------------------------------------------
__global__ __launch_bounds__(256) void sort_kernel(const int* __restrict__ h,
                                                   int* __restrict__ sorted_idx) {
  int rb = blockIdx.x;
  const int* hp = h + (size_t)rb * SEQ;
  __shared__ unsigned char hs[SEQ];
  __shared__ int tile_cnt[64][64];
  __shared__ int tile_base[64][64];
  __shared__ int bucket_base[64];
  __shared__ int bucket_tot[64];
  for (int i = threadIdx.x; i < 64 * 64; i += 256) ((int*)tile_cnt)[i] = 0;
  __syncthreads();
  for (int s = threadIdx.x; s < SEQ; s += 256) {
    int hv = hp[s] - 1;
    hs[s] = (unsigned char)hv;
    atomicAdd(&tile_cnt[s >> 6][hv], 1);
  }
  __syncthreads();
  if (threadIdx.x < 64) {
    int bkt = threadIdx.x;
    int run = 0;
    for (int t = 0; t < 64; ++t) { tile_base[t][bkt] = run; run += tile_cnt[t][bkt]; }
    bucket_tot[bkt] = run;
  }
  __syncthreads();
  if (threadIdx.x == 0) {
    int run = 0;
    for (int bkt = 0; bkt < 64; ++bkt) { bucket_base[bkt] = run; run += bucket_tot[bkt]; }
  }
  __syncthreads();
  for (int s = threadIdx.x; s < SEQ; s += 256) {
    int t = s >> 6;
    int bkt = hs[s];
    int rank = 0;
    for (int j = t << 6; j < s; ++j) rank += (hs[j] == bkt) ? 1 : 0;
    int pos = bucket_base[bkt] + tile_base[t][bkt] + rank;
    sorted_idx[(size_t)rb * SEQ + pos] = s;
  }
}

// ---------------------------------------------------------------------------
// Kernel 3: chunked LSH attention, one round per launch (r=0 store, r=1 add).
// Block = (b, chunk n, head). 64 queries x 128 keys. fp32 math throughout;
// only V staged as bf16 (un-amplified error <= ~0.01 << 0.0825 threshold).
// LDS: A (33.8 KB) holds K fp32 then S fp32; Bq (16.9 KB) holds Q fp32 then
// V bf16. -log(cnt) bias constant per row over valid keys -> cancels.
// OUTPUT IS FP32 (reference returns float32; harness reads d_out as fp32).
// ---------------------------------------------------------------------------
__global__ __launch_bounds__(256) void attn_kernel(
    const float* __restrict__ q, const float* __restrict__ k,
    const float* __restrict__ v, const int* __restrict__ h,
    const int* __restrict__ sidx, float* __restrict__ out, int r,
    int accumulate) {
  int x = blockIdx.x;
  int hd = x & 7;
  int n = (x >> 3) & 63;
  int b = x >> 9;
  int rb = r * BATCH + b;

  __shared__ float A[128 * 66];   // 33792 B: K fp32 (128x66) -> S fp32 (64x130)
  __shared__ float Bq[64 * 66];   // 16896 B: Q fp32 (64x66) -> V bf16 (128x66)
  __shared__ int orig_w[128];
  __shared__ int hw[128];
  bf16* Vv = reinterpret_cast<bf16*>(Bq);

  int tid = threadIdx.x;
  if (tid < 128) {
    int j = tid;
    int sp = (j < 64) ? ((((n + 63) & 63) << 6) + j) : ((n << 6) + (j - 64));
    int orig = sidx[(size_t)rb * SEQ + sp];
    orig_w[j] = orig;
    hw[j] = h[(size_t)rb * SEQ + orig];
  }
  __syncthreads();

  // Stage K (128-row window) and Q (current 64 rows), fp32, stride 66.
  for (int idx = tid; idx < 128 * 16; idx += 256) {
    int j = idx >> 4, dq = idx & 15;
    float4 kk = *reinterpret_cast<const float4*>(
        k + ((size_t)b * SEQ + orig_w[j]) * DM + hd * 64 + dq * 4);
    float* dst = &A[j * 66 + dq * 4];
    dst[0] = kk.x; dst[1] = kk.y; dst[2] = kk.z; dst[3] = kk.w;
  }
  for (int idx = tid; idx < 64 * 16; idx += 256) {
    int i = idx >> 4, dq = idx & 15;
    float4 qq = *reinterpret_cast<const float4*>(
        q + ((size_t)b * SEQ + orig_w[64 + i]) * DM + hd * 64 + dq * 4);
    float* dst = &Bq[i * 66 + dq * 4];
    dst[0] = qq.x; dst[1] = qq.y; dst[2] = qq.z; dst[3] = qq.w;
  }
  __syncthreads();

  // QK^T: thread computes a 4q x 8k register tile (fp32).
  int qt = tid & 15, kt = tid >> 4;
  int q0 = qt * 4, k0 = kt * 8;
  float acc[4][8];
#pragma unroll
  for (int qq = 0; qq < 4; ++qq)
#pragma unroll
    for (int jj = 0; jj < 8; ++jj) acc[qq][jj] = 0.f;

  for (int d = 0; d < 64; ++d) {
    float kreg[8];
#pragma unroll
    for (int jj = 0; jj < 8; ++jj) kreg[jj] = A[(k0 + jj) * 66 + d];
#pragma unroll
    for (int qq = 0; qq < 4; ++qq) {
      float qv = Bq[(q0 + qq) * 66 + d];
#pragma unroll
      for (int jj = 0; jj < 8; ++jj) acc[qq][jj] = fmaf(qv, kreg[jj], acc[qq][jj]);
    }
  }
  // Scale + masks (in registers; K/Q still live in LDS until the barrier).
#pragma unroll
  for (int qq = 0; qq < 4; ++qq) {
    int i = q0 + qq;
    int hq = hw[64 + i];
#pragma unroll
    for (int jj = 0; jj < 8; ++jj) {
      int j = k0 + jj;
      float lg = acc[qq][jj] * 0.125f;
      if (hw[j] != hq) lg = -1e15f;   // bucket mask
      if (j == 64 + i) lg -= 1e5f;    // self mask (diagonal of 128-window)
      acc[qq][jj] = lg;
    }
  }
  __syncthreads();  // all K/Q reads complete

  // Write S into A (stride 130); load V (bf16) into Bq's bytes.
#pragma unroll
  for (int qq = 0; qq < 4; ++qq)
#pragma unroll
    for (int jj = 0; jj < 8; ++jj) A[(q0 + qq) * 130 + k0 + jj] = acc[qq][jj];
  for (int idx = tid; idx < 128 * 16; idx += 256) {
    int j = idx >> 4, dq = idx & 15;
    float4 vv = *reinterpret_cast<const float4*>(
        v + ((size_t)b * SEQ + orig_w[j]) * DM + hd * 64 + dq * 4);
    bf16* dst = &Vv[j * 66 + dq * 4];
    dst[0] = __float2bfloat16(vv.x);
    dst[1] = __float2bfloat16(vv.y);
    dst[2] = __float2bfloat16(vv.z);
    dst[3] = __float2bfloat16(vv.w);
  }
  __syncthreads();

  // Softmax over 128 keys: 4 threads per row (segments of 32), fp32.
  {
    int row = tid >> 2, seg = tid & 3;
    float* Srow = A + row * 130 + seg * 32;
    float mx = -INFINITY;
#pragma unroll 8
    for (int t = 0; t < 32; ++t) mx = fmaxf(mx, Srow[t]);
    mx = fmaxf(mx, __shfl_xor(mx, 1));
    mx = fmaxf(mx, __shfl_xor(mx, 2));
    float sm = 0.f;
#pragma unroll 8
    for (int t = 0; t < 32; ++t) {
      float ev = __expf(Srow[t] - mx);
      Srow[t] = ev;
      sm += ev;
    }
    sm += __shfl_xor(sm, 1);
    sm += __shfl_xor(sm, 2);
    float inv = 1.0f / sm;
#pragma unroll 8
    for (int t = 0; t < 32; ++t) Srow[t] *= inv;
  }
  __syncthreads();

  // P @ V: thread computes a 4q x 4dv register tile.
  int dv0 = (tid >> 4) * 4;  // q0 unchanged
  float o[4][4];
#pragma unroll
  for (int qq = 0; qq < 4; ++qq)
#pragma unroll
    for (int dd = 0; dd < 4; ++dd) o[qq][dd] = 0.f;

  for (int l = 0; l < 128; ++l) {
    float vv[4];
#pragma unroll
    for (int dd = 0; dd < 4; ++dd) vv[dd] = b2f(Vv[l * 66 + dv0 + dd]);
#pragma unroll
    for (int qq = 0; qq < 4; ++qq) {
      float pv = A[(q0 + qq) * 130 + l];
#pragma unroll
      for (int dd = 0; dd < 4; ++dd) o[qq][dd] = fmaf(pv, vv[dd], o[qq][dd]);
    }
  }

  // FP32 output, scatter back through the inverse permutation.
#pragma unroll
  for (int qq = 0; qq < 4; ++qq) {
    int i = q0 + qq;
    size_t base = ((size_t)b * SEQ + orig_w[64 + i]) * DM + hd * 64 + dv0;
    if (accumulate) {
#pragma unroll
      for (int dd = 0; dd < 4; ++dd) out[base + dd] += o[qq][dd];
    } else {
#pragma unroll
      for (int dd = 0; dd < 4; ++dd) out[base + dd] = o[qq][dd];
    }
  }
}

extern "C" void kernel_launch(void* const* d_in, const int* in_sizes, int n_in,
                              void* d_out, int out_size, void* d_ws,
                              size_t ws_size, hipStream_t stream) {
  (void)out_size; (void)ws_size;
  const int R_ELEMS = ROUNDS * DM * 32;
  const float *q, *k, *v, *R;
  if (n_in >= 4 && in_sizes[0] == R_ELEMS) {  // defensive; dict order is live
    R = (const float*)d_in[0];
    k = (const float*)d_in[1];
    q = (const float*)d_in[2];
    v = (const float*)d_in[3];
  } else {
    q = (const float*)d_in[0];
    k = (const float*)d_in[1];
    v = (const float*)d_in[2];
    R = (const float*)d_in[3];
  }
  float* out = (float*)d_out;  // REFERENCE OUTPUT IS FP32
  char* ws = (char*)d_ws;
  int* h = (int*)ws;                                   // 128 KB
  int* sidx = (int*)(ws + ROUNDS * BATCH * SEQ * 4);   // 128 KB

  hash_kernel<<<ROUNDS * BATCH * (SEQ / 64), 256, 0, stream>>>(q, R, h);
  sort_kernel<<<ROUNDS * BATCH, 256, 0, stream>>>(h, sidx);
  attn_kernel<<<BATCH * NCHUNK * HEADS, 256, 0, stream>>>(q, k, v, h, sidx, out, 0, 0);
  attn_kernel<<<BATCH * NCHUNK * HEADS, 256, 0, stream>>>(q, k, v, h, sidx, out, 1, 1);
}